// Round 7
// baseline (315.985 us; speedup 1.0000x reference)
//
#include <hip/hip_runtime.h>

typedef __bf16 bf16x8 __attribute__((ext_vector_type(8)));
typedef float f32x16 __attribute__((ext_vector_type(16)));

__device__ __forceinline__ unsigned short f2bf(float f) {
    union { float f; unsigned u; } v; v.f = f;
    unsigned r = (v.u + 0x7FFFu + ((v.u >> 16) & 1u)) >> 16;
    return (unsigned short)r;
}
// pack two f32 -> one u32 of 2x bf16 (RNE; compiler fuses to v_cvt_pk_bf16_f32)
__device__ __forceinline__ unsigned pk2(float lo, float hi) {
    union { unsigned u; __bf16 h[2]; } t;
    t.h[0] = (__bf16)lo; t.h[1] = (__bf16)hi; return t.u;
}

// ---- weight conversion into MFMA fragment order (32x32x16 bf16) ----
// Frag mapping: lane l holds W[k0 + (l>>5)*8 + j][n0 + (l&31)], j=0..7.
// W1F index = ((g*8 + kb)*64 + l)*8 + j   (g: hidden col-group 0..31, kb: K-step 0..7, K pad 119->128)
// W2F index = ((gn*64 + kb)*64 + l)*8 + j (gn: out col-group 0..7, kb: K-step 0..63)
__global__ void conv_w(const float* __restrict__ W1, const float* __restrict__ W2,
                       unsigned short* __restrict__ W1F, unsigned short* __restrict__ W2F) {
    int b = blockIdx.x;
    if (b < 512) {
        int idx = b * 256 + threadIdx.x;                   // 131072
        int j = idx & 7, l = (idx >> 3) & 63, kb = (idx >> 9) & 7, g = idx >> 12;
        int k = kb * 16 + (l >> 5) * 8 + j;
        int h = g * 32 + (l & 31);
        float v = (k < 119) ? W1[(size_t)k * 1024 + h] : 0.0f;
        W1F[idx] = f2bf(v);
    } else {
        int idx = (b - 512) * 256 + threadIdx.x;           // 262144
        int j = idx & 7, l = (idx >> 3) & 63, kb = (idx >> 9) & 63, gn = idx >> 15;
        int k = kb * 16 + (l >> 5) * 8 + j;
        int n = gn * 32 + (l & 31);
        W2F[idx] = f2bf(W2[(size_t)k * 256 + n]);
    }
}

// ---- fused features + MLP: PRODUCER/CONSUMER wave specialization ----
// 512 threads (8 waves), 64 rows/block, grid 2048. chunk = 128 hidden cols (8 chunks).
// Waves 0-3 (A): features + phase A (W1 VMEM stream + MFMA + packswap + H write).
// Waves 4-7 (B): phase B (H ds_read + W2 VMEM stream + MFMA) one chunk behind.
// Double-buffered frag-ordered H; ONE s_barrier per chunk; lgkm-only fence (vmcnt
// never drained at barriers). VMEM-heavy A overlaps LDS/MFMA-heavy B structurally --
// no manual vmcnt pinning (R4), no reg-keep branch (R6), compiler-scheduled (R2).
// All main-loop LDS is fragment-ordered (addr = base + lane*16): zero bank conflicts (R5).
__global__ __launch_bounds__(512, 2) void mlp_fused(
    const float* __restrict__ hole, const float* __restrict__ board,
    const float* __restrict__ b1, const float* __restrict__ b2,
    const unsigned short* __restrict__ W1F, const unsigned short* __restrict__ W2F,
    float* __restrict__ out)
{
    __shared__ unsigned short Xsf[16 * 512];   // 16KB frag-ordered X: ((mi*8+ks)*64+lane)*8
    __shared__ unsigned short HsF[2][8192];    // 2 x 16KB frag-ordered H: ((mi*8+kc)*64+lane)*8
    // rowmajX (64 rows x 128 shorts) aliases HsF[0] during init only

    const int tid  = threadIdx.x;
    const int w    = tid >> 6;       // 0..7
    const int wa   = w & 3;          // A-wave id (hg owner) / B-wave id (N-pair owner)
    const bool isA = (w < 4);
    const int lane = tid & 63;
    const int l32  = lane & 31;
    const int hi   = lane >> 5;      // 0/1 half-wave
    const long r0  = (long)blockIdx.x * 64;
    const int crot = (int)((blockIdx.x + (blockIdx.x >> 8)) & 7);

    // ---------------- feature extraction: thread t < 64 handles row r0+t ----------------
    if (tid < 64) {
        const long r = r0 + tid;
        const float4* hp = (const float4*)(hole + r * 52);
        const float4* bp = (const float4*)(board + r * 52);
        unsigned long long hm = 0ull, bm = 0ull;
        #pragma unroll
        for (int i = 0; i < 13; ++i) {
            float4 h4 = hp[i], b4 = bp[i];
            int base = i * 4;
            hm |= ((unsigned long long)(h4.x > 0.5f)) << (base + 0);
            hm |= ((unsigned long long)(h4.y > 0.5f)) << (base + 1);
            hm |= ((unsigned long long)(h4.z > 0.5f)) << (base + 2);
            hm |= ((unsigned long long)(h4.w > 0.5f)) << (base + 3);
            bm |= ((unsigned long long)(b4.x > 0.5f)) << (base + 0);
            bm |= ((unsigned long long)(b4.y > 0.5f)) << (base + 1);
            bm |= ((unsigned long long)(b4.z > 0.5f)) << (base + 2);
            bm |= ((unsigned long long)(b4.w > 0.5f)) << (base + 3);
        }
        const unsigned long long am = hm | bm;
        const int bcount = __popcll(bm);
        const int hcount = __popcll(hm);

        int pairs_b = 0, pairs_a = 0;
        bool trips_b = false, trips_a = false;
        unsigned prb = 0, pra = 0;
        #pragma unroll
        for (int rr = 0; rr < 13; ++rr) {
            int cb = __popc((unsigned)((bm >> (4 * rr)) & 0xFull));
            int ca = __popc((unsigned)((am >> (4 * rr)) & 0xFull));
            pairs_b += (cb >= 2); trips_b = trips_b || (cb >= 3); prb |= (unsigned)(cb > 0) << rr;
            pairs_a += (ca >= 2); trips_a = trips_a || (ca >= 3); pra |= (unsigned)(ca > 0) << rr;
        }
        const unsigned long long SM = 0x1111111111111ull;
        int bscm = 0, ascm = 0;
        #pragma unroll
        for (int s = 0; s < 4; ++s) {
            int bs = __popcll(bm & (SM << s));
            int as = __popcll(am & (SM << s));
            bscm = bs > bscm ? bs : bscm;
            ascm = as > ascm ? as : ascm;
        }
        float strength = trips_b ? 0.8f : (pairs_b >= 2 ? 0.6f : (pairs_b >= 1 ? 0.4f : 0.2f));
        if (bcount == 0) strength = 0.0f;
        float flush_b = (bscm >= 3 && bcount > 0) ? 1.0f : 0.0f;
        bool sb = false;
        #pragma unroll
        for (int i = 0; i < 13; ++i) sb = sb || (__popc((prb >> i) & 0x1Fu) >= 3);
        float straight_b = (sb && bcount > 0) ? 1.0f : 0.0f;
        float gr0 = (bcount == 0) ? 1.0f : 0.0f;
        float gr3 = (bcount == 3) ? 1.0f : 0.0f;
        float gr4 = (bcount == 4) ? 1.0f : 0.0f;
        float gr5 = (bcount == 5) ? 1.0f : 0.0f;
        float valid = (hcount >= 2 && bcount >= 1) ? 1.0f : 0.0f;
        float flush_draw = (ascm == 4) ? 1.0f : 0.0f;
        float flush_outs = fmaxf(0.0f, 13.0f - (float)ascm) * (1.0f / 13.0f);
        int first = -1;
        #pragma unroll
        for (int i = 0; i < 13; ++i) {
            bool qq = (((pra >> i) & 1u) != 0u) && (__popc((pra >> i) & 0x1Fu) >= 4);
            if (qq && first < 0) first = i;
        }
        float straight_draw = (first >= 0) ? 1.0f : 0.0f;
        float straight_outs = 0.0f;
        if (first >= 0) {
            int c4 = __popc((pra >> first) & 0xFu);
            straight_outs = (c4 >= 4) ? 0.4f : 0.2f;
        }
        float total_outs = flush_draw * flush_outs * 9.0f + straight_draw * straight_outs * 8.0f;
        float remaining = 52.0f - (float)(hcount + bcount);
        float equity = 0.0f;
        if (remaining > 0.0f) equity = fminf(1.0f, total_outs / fmaxf(remaining, 1.0f));
        float hit_pair  = (pairs_a >= 1) ? 1.0f : 0.0f;
        float hit_trips = trips_a ? 1.0f : 0.0f;
        float hit_two   = (pairs_a >= 2) ? 1.0f : 0.0f;

        unsigned short* xrow = &HsF[0][tid * 128];   // row-major X temp (aliases HsF[0])
        #pragma unroll
        for (int i = 0; i < 52; ++i) xrow[i]      = ((hm >> i) & 1ull) ? (unsigned short)0x3F80 : (unsigned short)0;
        #pragma unroll
        for (int i = 0; i < 52; ++i) xrow[52 + i] = ((bm >> i) & 1ull) ? (unsigned short)0x3F80 : (unsigned short)0;
        float feats[15] = { strength, flush_b, straight_b, gr0, gr3, gr4, gr5,
                            valid * flush_draw, valid * flush_outs, valid * straight_draw,
                            valid * straight_outs, valid * equity,
                            valid * hit_pair, valid * hit_trips, valid * hit_two };
        #pragma unroll
        for (int i = 0; i < 15; ++i) xrow[104 + i] = f2bf(feats[i]);
        #pragma unroll
        for (int i = 119; i < 128; ++i) xrow[i] = 0;
    }

    __syncthreads();   // rowmajX visible

    // ---- one-time conversion: row-major X -> frag-ordered Xsf (A-wave wa builds ks={2wa,2wa+1}) ----
    if (isA) {
        bf16x8 cf[2][2];
        #pragma unroll
        for (int mi = 0; mi < 2; ++mi)
            #pragma unroll
            for (int jj = 0; jj < 2; ++jj) {
                const int ks = 2 * wa + jj;
                cf[mi][jj] = *(const bf16x8*)&HsF[0][(mi * 32 + l32) * 128 + ks * 16 + hi * 8];
            }
        __syncthreads();   // conversion reads done (HsF[0] free for H)
        #pragma unroll
        for (int mi = 0; mi < 2; ++mi)
            #pragma unroll
            for (int jj = 0; jj < 2; ++jj)
                *(bf16x8*)&Xsf[((mi * 8 + 2 * wa + jj) * 64 + lane) * 8] = cf[mi][jj];
    } else {
        __syncthreads();
    }
    __syncthreads();   // Xsf visible

    f32x16 acc[2][2];   // B-waves only (A-waves never touch after init)
    #pragma unroll
    for (int a = 0; a < 2; ++a)
        #pragma unroll
        for (int b = 0; b < 2; ++b)
            #pragma unroll
            for (int r = 0; r < 16; ++r) acc[a][b][r] = 0.0f;

    // ---- phase A body: chunk cn -> buf (A-wave wa owns hg=wa => kc pair {2wa,2wa+1}) ----
    auto phaseA = [&](int cn, unsigned short* buf) {
        const unsigned short* w1p = W1F + ((size_t)(cn * 4 + wa) * 8) * 512 + lane * 8;
        f32x16 h0, h1;
        #pragma unroll
        for (int r = 0; r < 16; ++r) { h0[r] = 0.0f; h1[r] = 0.0f; }
        #pragma unroll
        for (int ks = 0; ks < 8; ++ks) {
            bf16x8 wfr = *(const bf16x8*)(w1p + ks * 512);
            bf16x8 x0 = *(const bf16x8*)&Xsf[((0 * 8 + ks) * 64 + lane) * 8];
            bf16x8 x1 = *(const bf16x8*)&Xsf[((1 * 8 + ks) * 64 + lane) * 8];
            h0 = __builtin_amdgcn_mfma_f32_32x32x16_bf16(wfr, x0, h0, 0, 0, 0);
            h1 = __builtin_amdgcn_mfma_f32_32x32x16_bf16(wfr, x1, h1, 0, 0, 0);
        }
        float4 bq[4];
        #pragma unroll
        for (int q = 0; q < 4; ++q) bq[q] = *(const float4*)&b1[cn * 128 + wa * 32 + 8 * q + 4 * hi];
        // pack + bias/relu + lane^32 exchange -> phase-B A-frag layout
        #pragma unroll
        for (int mi = 0; mi < 2; ++mi) {
            const f32x16& h = mi ? h1 : h0;
            float v[16];
            #pragma unroll
            for (int q = 0; q < 4; ++q) {
                v[4 * q + 0] = fmaxf(h[4 * q + 0] + bq[q].x, 0.0f);
                v[4 * q + 1] = fmaxf(h[4 * q + 1] + bq[q].y, 0.0f);
                v[4 * q + 2] = fmaxf(h[4 * q + 2] + bq[q].z, 0.0f);
                v[4 * q + 3] = fmaxf(h[4 * q + 3] + bq[q].w, 0.0f);
            }
            unsigned p0 = pk2(v[0], v[1]),   p1 = pk2(v[2], v[3]);
            unsigned p2 = pk2(v[4], v[5]),   p3 = pk2(v[6], v[7]);
            unsigned p4 = pk2(v[8], v[9]),   p5 = pk2(v[10], v[11]);
            unsigned p6 = pk2(v[12], v[13]), p7 = pk2(v[14], v[15]);
            unsigned q0 = (unsigned)__shfl_xor((int)p0, 32, 64);
            unsigned q1 = (unsigned)__shfl_xor((int)p1, 32, 64);
            unsigned q2 = (unsigned)__shfl_xor((int)p2, 32, 64);
            unsigned q3 = (unsigned)__shfl_xor((int)p3, 32, 64);
            unsigned q4 = (unsigned)__shfl_xor((int)p4, 32, 64);
            unsigned q5 = (unsigned)__shfl_xor((int)p5, 32, 64);
            unsigned q6 = (unsigned)__shfl_xor((int)p6, 32, 64);
            unsigned q7 = (unsigned)__shfl_xor((int)p7, 32, 64);
            uint4 f0, f1;
            f0.x = hi ? q2 : p0;  f0.y = hi ? q3 : p1;  f0.z = hi ? p2 : q0;  f0.w = hi ? p3 : q1;
            f1.x = hi ? q6 : p4;  f1.y = hi ? q7 : p5;  f1.z = hi ? p6 : q4;  f1.w = hi ? p7 : q5;
            *(uint4*)&buf[((mi * 8 + 2 * wa + 0) * 64 + lane) * 8] = f0;
            *(uint4*)&buf[((mi * 8 + 2 * wa + 1) * 64 + lane) * 8] = f1;
        }
    };

    // ---- prologue: A-waves produce chunk crot -> HsF[0] ----
    if (isA) phaseA(crot, &HsF[0][0]);
    asm volatile("s_waitcnt lgkmcnt(0)" ::: "memory");
    __builtin_amdgcn_s_barrier();

    // ---- main loop: one barrier per chunk; A one chunk ahead of B ----
    for (int i = 0; i < 8; ++i) {
        if (isA) {
            if (i < 7) phaseA((crot + i + 1) & 7, &HsF[(i + 1) & 1][0]);
        } else {
            // ---- phase B, chunk cc = (crot+i)&7, reads HsF[i&1] ----
            const int cc = (crot + i) & 7;
            const unsigned short* hbase = &HsF[i & 1][0];
            const unsigned short* w2p0 = W2F + ((size_t)(2 * wa + 0) * 64 + cc * 8) * 512 + lane * 8;
            const unsigned short* w2p1 = W2F + ((size_t)(2 * wa + 1) * 64 + cc * 8) * 512 + lane * 8;
            #pragma unroll
            for (int kc = 0; kc < 8; ++kc) {
                bf16x8 a0  = *(const bf16x8*)&hbase[((0 * 8 + kc) * 64 + lane) * 8];
                bf16x8 a1  = *(const bf16x8*)&hbase[((1 * 8 + kc) * 64 + lane) * 8];
                bf16x8 b0  = *(const bf16x8*)(w2p0 + kc * 512);
                bf16x8 b1f = *(const bf16x8*)(w2p1 + kc * 512);
                acc[0][0] = __builtin_amdgcn_mfma_f32_32x32x16_bf16(a0, b0,  acc[0][0], 0, 0, 0);
                acc[0][1] = __builtin_amdgcn_mfma_f32_32x32x16_bf16(a0, b1f, acc[0][1], 0, 0, 0);
                acc[1][0] = __builtin_amdgcn_mfma_f32_32x32x16_bf16(a1, b0,  acc[1][0], 0, 0, 0);
                acc[1][1] = __builtin_amdgcn_mfma_f32_32x32x16_bf16(a1, b1f, acc[1][1], 0, 0, 0);
            }
        }
        if (i < 7) {
            asm volatile("s_waitcnt lgkmcnt(0)" ::: "memory");   // A: H(i+1) writes done; B: H(i) reads done
            __builtin_amdgcn_s_barrier();                        // vmcnt NOT drained
        }
    }

    // ---- epilogue (B-waves): + b2, store f32 ----
    if (!isA) {
        #pragma unroll
        for (int ni = 0; ni < 2; ++ni) {
            const int col = (2 * wa + ni) * 32 + l32;
            const float bb = b2[col];
            #pragma unroll
            for (int mi = 0; mi < 2; ++mi) {
                #pragma unroll
                for (int r = 0; r < 16; ++r) {
                    const long row = r0 + mi * 32 + (r & 3) + 8 * (r >> 2) + 4 * hi;
                    out[row * 256 + col] = acc[mi][ni][r] + bb;
                }
            }
        }
    }
}

extern "C" void kernel_launch(void* const* d_in, const int* in_sizes, int n_in,
                              void* d_out, int out_size, void* d_ws, size_t ws_size,
                              hipStream_t stream) {
    (void)in_sizes; (void)n_in; (void)out_size; (void)ws_size;
    const float* hole  = (const float*)d_in[0];
    const float* board = (const float*)d_in[1];
    const float* W1    = (const float*)d_in[2];
    const float* b1    = (const float*)d_in[3];
    const float* W2    = (const float*)d_in[4];
    const float* b2    = (const float*)d_in[5];
    float* out = (float*)d_out;

    unsigned short* W1F = (unsigned short*)d_ws;            // 131072 bf16 = 256 KB
    unsigned short* W2F = W1F + 131072;                     // 262144 bf16 = 512 KB

    conv_w<<<1536, 256, 0, stream>>>(W1, W2, W1F, W2F);
    mlp_fused<<<131072 / 64, 512, 0, stream>>>(hole, board, b1, b2, W1F, W2F, out);
}